// Round 2
// baseline (2034.196 us; speedup 1.0000x reference)
//
#include <hip/hip_runtime.h>
#include <hip/hip_bf16.h>

typedef __bf16 bf16_t;
typedef __bf16 bf16x4 __attribute__((ext_vector_type(4)));
typedef __bf16 bf16x8 __attribute__((ext_vector_type(8)));
typedef float  f32x4  __attribute__((ext_vector_type(4)));

#define NH    6
#define CH    192
#define HW    112
#define SHIFT 3

// LDS strides (bf16 elements). Row strides give <=2-way bank aliasing on
// ds_read_b128 (free per m136): XLD=200 -> 4-bank row step; VLD=88 -> 12-bank.
#define XLD 200   // X/Q/K/O tiles: [64][200]
#define VLD 88    // Vt [192][88], P [64][88]

#define X_OFF   0
#define Q_OFF   (64 * XLD)            // Q buffer doubles as O
#define K_OFF   (Q_OFF + 64 * XLD)
#define VT_OFF  (K_OFF + 64 * XLD)
#define P_OFF   (VT_OFF + 192 * VLD)
#define LDS_ELEMS (P_OFF + 64 * VLD)
#define LDS_BYTES (LDS_ELEMS * 2)     // 121856 B (<160 KiB/CU, 1 block/CU)

// ---- weight prep: transpose + f32->bf16 into ws ----------------------------
//   m<3 : wts[m][h][d_out][c_in] = W[c_in][h][d_out]   (A-operand = W^T)
//   m==3: wts[3][h][c_out][d_in] = Wo[h][d_in][c_out]  (A-operand = Wo^T)
__global__ void prep_w(const float* __restrict__ Wq, const float* __restrict__ Wk,
                       const float* __restrict__ Wv, const float* __restrict__ Wo,
                       bf16_t* __restrict__ out) {
  int idx = blockIdx.x * 256 + threadIdx.x;
  const int per = NH * CH * CH;
  if (idx >= 4 * per) return;
  int m = idx / per, r = idx % per;
  int h = r / (CH * CH), r2 = r % (CH * CH);
  int a = r2 / CH, k = r2 % CH;
  float v;
  if (m == 0)      v = Wq[(k * NH + h) * CH + a];
  else if (m == 1) v = Wk[(k * NH + h) * CH + a];
  else if (m == 2) v = Wv[(k * NH + h) * CH + a];
  else             v = Wo[(h * CH + k) * CH + a];
  out[idx] = (bf16_t)v;
}

// ---- fused swin block: one workgroup per 7x7 window, 16 waves --------------
__global__ __launch_bounds__(1024) void swin_fused(
    const float* __restrict__ x,
    const float* __restrict__ bq, const float* __restrict__ bk,
    const float* __restrict__ bv, const float* __restrict__ bo,
    const bf16_t* __restrict__ wts,
    float* __restrict__ out) {
  extern __shared__ char smem_raw[];
  bf16_t* lds = (bf16_t*)smem_raw;
  bf16_t* Xl  = lds + X_OFF;
  bf16_t* Ql  = lds + Q_OFF;   // also O
  bf16_t* Kl  = lds + K_OFF;
  bf16_t* Vtl = lds + VT_OFF;
  bf16_t* Pl  = lds + P_OFF;

  const int tid  = threadIdx.x;
  const int wave = tid >> 6;           // 0..15
  const int lane = tid & 63;
  const int l15  = lane & 15;
  const int lg   = lane >> 4;          // 0..3

  const int blk = blockIdx.x;
  const int b   = blk >> 8;            // batch
  const int rem = blk & 255;           // window within batch
  const int wi  = rem >> 4, wj = rem & 15;

  // zero pad rows 49..63 of X
  for (int idx = tid; idx < 15 * 100; idx += 1024) {
    int row = 49 + idx / 100, c2 = (idx % 100) * 2;
    *(unsigned int*)&Xl[row * XLD + c2] = 0u;
  }
  // stage window tokens (roll -3,-3 folded into the gather), f32 -> bf16
  for (int idx = tid; idx < 49 * 48; idx += 1024) {
    int t = idx / 48, q4 = idx % 48;
    int hs = wi * 7 + t / 7 + SHIFT; if (hs >= HW) hs -= HW;
    int ws2 = wj * 7 + t % 7 + SHIFT; if (ws2 >= HW) ws2 -= HW;
    const float4 v = *(const float4*)&x[(((b * HW + hs) * HW) + ws2) * CH + q4 * 4];
    bf16x4 pk = { (bf16_t)v.x, (bf16_t)v.y, (bf16_t)v.z, (bf16_t)v.w };
    *(bf16x4*)&Xl[t * XLD + q4 * 4] = pk;
  }

  // phase C/D wave decomposition: wc picks 3 m-tiles (of 12), wt4 picks n-tile
  const int wc  = wave >> 2;           // 0..3
  const int wt4 = wave & 3;            // 0..3
  f32x4 yacc[3] = {};                  // persistent out-proj accumulators

  for (int h = 0; h < NH; ++h) {
    __syncthreads();
    // ---- Phase A: Q^T-GEMM (waves 0-7) / K^T-GEMM (waves 8-15)
    // D[d,t] = sum_c W^T[d,c] * X[t,c]; packed b64 write into [t][d] row-major.
    {
      const int isK = wave >> 3;
      const int w8  = wave & 7;
      const int wm  = w8 >> 1;         // m-block: 3 tiles
      const int wn  = (w8 & 1) * 2;    // n-tile base: 2 tiles
      const bf16_t* wt = wts + ((isK * NH + h) * CH * CH);
      const float* bias = (isK ? bk : bq) + h * CH;
      bf16_t* dst = isK ? Kl : Ql;
      f32x4 acc[3][2] = {};
#pragma unroll
      for (int ks = 0; ks < 6; ++ks) {
        bf16x8 af[3], bfr[2];
#pragma unroll
        for (int mi = 0; mi < 3; ++mi) {
          int d = (wm * 3 + mi) * 16 + l15;
          af[mi] = *(const bf16x8*)&wt[d * CH + ks * 32 + lg * 8];
        }
#pragma unroll
        for (int ni = 0; ni < 2; ++ni)
          bfr[ni] = *(const bf16x8*)&Xl[((wn + ni) * 16 + l15) * XLD + ks * 32 + lg * 8];
#pragma unroll
        for (int mi = 0; mi < 3; ++mi)
#pragma unroll
          for (int ni = 0; ni < 2; ++ni)
            acc[mi][ni] = __builtin_amdgcn_mfma_f32_16x16x32_bf16(af[mi], bfr[ni], acc[mi][ni], 0, 0, 0);
      }
#pragma unroll
      for (int mi = 0; mi < 3; ++mi) {
        int d0 = (wm * 3 + mi) * 16 + lg * 4;
        float b0 = bias[d0], b1 = bias[d0 + 1], b2 = bias[d0 + 2], b3 = bias[d0 + 3];
#pragma unroll
        for (int ni = 0; ni < 2; ++ni) {
          int t = (wn + ni) * 16 + l15;
          bf16x4 pk = { (bf16_t)(acc[mi][ni][0] + b0), (bf16_t)(acc[mi][ni][1] + b1),
                        (bf16_t)(acc[mi][ni][2] + b2), (bf16_t)(acc[mi][ni][3] + b3) };
          *(bf16x4*)&dst[t * XLD + d0] = pk;
        }
      }
    }
    __syncthreads();
    // ---- Phase B: V-GEMM (waves 0-11) || scores + in-register softmax (waves 12-15)
    if (wave < 12) {
      // V[t,d] = sum_c X[t,c] Wv^T[d,c]; wave owns d-tile `wave`; write Vt[d][t].
      const bf16_t* wt = wts + ((2 * NH + h) * CH * CH);
      const int d = wave * 16 + l15;
      const float bb = bv[h * CH + d];
      f32x4 acc[4] = {};
#pragma unroll
      for (int ks = 0; ks < 6; ++ks) {
        bf16x8 af[4];
#pragma unroll
        for (int mi = 0; mi < 4; ++mi)
          af[mi] = *(const bf16x8*)&Xl[(mi * 16 + l15) * XLD + ks * 32 + lg * 8];
        bf16x8 bfr = *(const bf16x8*)&wt[d * CH + ks * 32 + lg * 8];
#pragma unroll
        for (int mi = 0; mi < 4; ++mi)
          acc[mi] = __builtin_amdgcn_mfma_f32_16x16x32_bf16(af[mi], bfr, acc[mi], 0, 0, 0);
      }
#pragma unroll
      for (int mi = 0; mi < 4; ++mi) {
        int t0 = mi * 16 + lg * 4;
        bf16x4 pk = { (bf16_t)(acc[mi][0] + bb), (bf16_t)(acc[mi][1] + bb),
                      (bf16_t)(acc[mi][2] + bb), (bf16_t)(acc[mi][3] + bb) };
        *(bf16x4*)&Vtl[d * VLD + t0] = pk;
      }
    } else {
      // S^[j,i] = sum_d K[j,d] Q[i,d]; lane owns col i, rows j in registers.
      const int it = wave - 12;
      f32x4 sacc[4] = {};
#pragma unroll
      for (int ks = 0; ks < 6; ++ks) {
        bf16x8 bq8 = *(const bf16x8*)&Ql[(it * 16 + l15) * XLD + ks * 32 + lg * 8];
#pragma unroll
        for (int mj = 0; mj < 4; ++mj) {
          bf16x8 ak = *(const bf16x8*)&Kl[(mj * 16 + l15) * XLD + ks * 32 + lg * 8];
          sacc[mj] = __builtin_amdgcn_mfma_f32_16x16x32_bf16(ak, bq8, sacc[mj], 0, 0, 0);
        }
      }
      const float scale = 0.07216878364870322f;  // 1/sqrt(192)
      float mx = -1e30f;
#pragma unroll
      for (int mj = 0; mj < 4; ++mj)
#pragma unroll
        for (int r = 0; r < 4; ++r) {
          int j = mj * 16 + lg * 4 + r;
          if (j < 49) mx = fmaxf(mx, sacc[mj][r]);
        }
      mx = fmaxf(mx, __shfl_xor(mx, 16));
      mx = fmaxf(mx, __shfl_xor(mx, 32));
      float p[4][4];
      float sum = 0.f;
#pragma unroll
      for (int mj = 0; mj < 4; ++mj)
#pragma unroll
        for (int r = 0; r < 4; ++r) {
          int j = mj * 16 + lg * 4 + r;
          float e = (j < 49) ? __expf((sacc[mj][r] - mx) * scale) : 0.f;
          p[mj][r] = e;
          sum += e;
        }
      sum += __shfl_xor(sum, 16);
      sum += __shfl_xor(sum, 32);
      float inv = 1.f / sum;
      int i = it * 16 + l15;
#pragma unroll
      for (int mj = 0; mj < 4; ++mj) {
        bf16x4 pk = { (bf16_t)(p[mj][0] * inv), (bf16_t)(p[mj][1] * inv),
                      (bf16_t)(p[mj][2] * inv), (bf16_t)(p[mj][3] * inv) };
        *(bf16x4*)&Pl[i * VLD + mj * 16 + lg * 4] = pk;
      }
    }
    __syncthreads();
    // ---- Phase C: O^T-GEMM. D[d,i] = sum_j Vt[d,j] P[i,j]; write O[i][d] over Q.
    {
      f32x4 acc[3] = {};
#pragma unroll
      for (int ks = 0; ks < 2; ++ks) {
        bf16x8 af[3];
#pragma unroll
        for (int mi = 0; mi < 3; ++mi)
          af[mi] = *(const bf16x8*)&Vtl[((wc * 3 + mi) * 16 + l15) * VLD + ks * 32 + lg * 8];
        bf16x8 bfr = *(const bf16x8*)&Pl[(wt4 * 16 + l15) * VLD + ks * 32 + lg * 8];
#pragma unroll
        for (int mi = 0; mi < 3; ++mi)
          acc[mi] = __builtin_amdgcn_mfma_f32_16x16x32_bf16(af[mi], bfr, acc[mi], 0, 0, 0);
      }
#pragma unroll
      for (int mi = 0; mi < 3; ++mi) {
        int d0 = (wc * 3 + mi) * 16 + lg * 4;
        int t  = wt4 * 16 + l15;
        bf16x4 pk = { (bf16_t)acc[mi][0], (bf16_t)acc[mi][1],
                      (bf16_t)acc[mi][2], (bf16_t)acc[mi][3] };
        *(bf16x4*)&Ql[t * XLD + d0] = pk;
      }
    }
    __syncthreads();
    // ---- Phase D: Y^T accumulate. yacc[c,t] += sum_d Wo^T[c,d] O[t,d].
    {
      const bf16_t* wt = wts + ((3 * NH + h) * CH * CH);
#pragma unroll
      for (int ks = 0; ks < 6; ++ks) {
        bf16x8 af[3];
#pragma unroll
        for (int mi = 0; mi < 3; ++mi) {
          int c = (wc * 3 + mi) * 16 + l15;
          af[mi] = *(const bf16x8*)&wt[c * CH + ks * 32 + lg * 8];
        }
        bf16x8 bfr = *(const bf16x8*)&Ql[(wt4 * 16 + l15) * XLD + ks * 32 + lg * 8];
#pragma unroll
        for (int mi = 0; mi < 3; ++mi)
          yacc[mi] = __builtin_amdgcn_mfma_f32_16x16x32_bf16(af[mi], bfr, yacc[mi], 0, 0, 0);
      }
    }
  }

  // ---- epilogue: +bo, plain-reshape merge + roll(+3,+3), packed f32x4 stores
  {
    int t = wt4 * 16 + l15;
    if (t < 49) {
      int pos = rem * 49 + t;
      int hp = pos / 112, wp = pos % 112;
      hp += SHIFT; if (hp >= HW) hp -= HW;
      wp += SHIFT; if (wp >= HW) wp -= HW;
      float* op = out + (((b * HW + hp) * HW) + wp) * CH;
#pragma unroll
      for (int mi = 0; mi < 3; ++mi) {
        int c0 = (wc * 3 + mi) * 16 + lg * 4;
        f32x4 v = yacc[mi];
        v[0] += bo[c0]; v[1] += bo[c0 + 1]; v[2] += bo[c0 + 2]; v[3] += bo[c0 + 3];
        *(f32x4*)&op[c0] = v;
      }
    }
  }
}

extern "C" void kernel_launch(void* const* d_in, const int* in_sizes, int n_in,
                              void* d_out, int out_size, void* d_ws, size_t ws_size,
                              hipStream_t stream) {
  const float* x  = (const float*)d_in[0];
  const float* Wq = (const float*)d_in[1];
  const float* bq = (const float*)d_in[2];
  const float* Wk = (const float*)d_in[3];
  const float* bk = (const float*)d_in[4];
  const float* Wv = (const float*)d_in[5];
  const float* bv = (const float*)d_in[6];
  const float* Wo = (const float*)d_in[7];
  const float* bo = (const float*)d_in[8];
  float* out = (float*)d_out;
  bf16_t* wts = (bf16_t*)d_ws;   // 4*6*192*192*2 = 1,769,472 B of ws

  prep_w<<<(4 * NH * CH * CH + 255) / 256, 256, 0, stream>>>(Wq, Wk, Wv, Wo, wts);

  (void)hipFuncSetAttribute((const void*)swin_fused,
                            hipFuncAttributeMaxDynamicSharedMemorySize, LDS_BYTES);
  swin_fused<<<dim3(4096), dim3(1024), LDS_BYTES, stream>>>(x, bq, bk, bv, bo, wts, out);
}

// Round 3
// 893.100 us; speedup vs baseline: 2.2777x; 2.2777x over previous
//
#include <hip/hip_runtime.h>
#include <hip/hip_bf16.h>

typedef __bf16 bf16_t;
typedef __bf16 bf16x4 __attribute__((ext_vector_type(4)));
typedef __bf16 bf16x8 __attribute__((ext_vector_type(8)));
typedef float  f32x4  __attribute__((ext_vector_type(4)));

#define NH    6
#define CH    192
#define HW    112
#define SHIFT 3

// LDS strides (bf16 elems). XLD=200 -> 400B row step (bank step 4, 2-way on
// b128, free per m136). ULD=72 -> 144B row step (bank step 4, same class).
#define XLD 200
#define ULD 72

#define X_OFF   0
#define Q_OFF   (64 * XLD)            // 12800
#define K_OFF   (2 * 64 * XLD)        // 25600
// P/VOt overlay the dead Q/K region after the phase-B read barrier:
#define P_OFF   Q_OFF                 // 64 x ULD
#define VOT_OFF (Q_OFF + 64 * ULD)    // 192 x ULD, ends at 31232 < 38400
#define LDS_ELEMS (3 * 64 * XLD)      // 38400
#define LDS_BYTES (LDS_ELEMS * 2)     // 76800 B -> 2 blocks/CU (153.6 < 160 KiB)

// ws layout: wts[0]=Wq^T, wts[1]=Wk^T, wts[2]=U^T (each NH*CH*CH bf16), then bu f32[NH*CH]
#define BU_OFF_BYTES (3 * NH * CH * CH * 2)

// ---- prep: Wq/Wk transposed to bf16 ---------------------------------------
__global__ void prep_w(const float* __restrict__ Wq, const float* __restrict__ Wk,
                       bf16_t* __restrict__ out) {
  int idx = blockIdx.x * 256 + threadIdx.x;
  const int per = NH * CH * CH;
  if (idx >= 2 * per) return;
  int m = idx / per, r = idx % per;
  int h = r / (CH * CH), r2 = r % (CH * CH);
  int a = r2 / CH, k = r2 % CH;
  const float* W = m ? Wk : Wq;
  out[idx] = (bf16_t)W[(k * NH + h) * CH + a];   // wts[m][h][d_out][c_in]
}

// ---- prep: U^h = Wv^h x Wo^h (value/out-proj fusion), stored U^T[c_out][c_in]
__global__ void prep_u(const float* __restrict__ Wv, const float* __restrict__ Wo,
                       bf16_t* __restrict__ u_out) {
  __shared__ float wv_row[CH];
  int h = blockIdx.x / CH, ci = blockIdx.x % CH;
  int t = threadIdx.x;                            // c_out
  wv_row[t] = Wv[(ci * NH + h) * CH + t];
  __syncthreads();
  float acc = 0.f;
  for (int d = 0; d < CH; ++d)
    acc += wv_row[d] * Wo[(h * CH + d) * CH + t];
  u_out[(h * CH + t) * CH + ci] = (bf16_t)acc;
}

// ---- prep: bu^h = bv^h x Wo^h ---------------------------------------------
__global__ void prep_bu(const float* __restrict__ bv, const float* __restrict__ Wo,
                        float* __restrict__ bu) {
  int h = blockIdx.x, c = threadIdx.x;
  float acc = 0.f;
  for (int d = 0; d < CH; ++d)
    acc += bv[h * CH + d] * Wo[(h * CH + d) * CH + c];
  bu[h * CH + c] = acc;
}

// ---- fused swin block: one workgroup per 7x7 window, 8 waves, 2 blocks/CU --
__global__ __launch_bounds__(512, 2) void swin_fused(
    const float* __restrict__ x,
    const float* __restrict__ bq, const float* __restrict__ bk,
    const float* __restrict__ bo,
    const bf16_t* __restrict__ wts, const float* __restrict__ bu,
    float* __restrict__ out) {
  extern __shared__ char smem_raw[];
  bf16_t* lds  = (bf16_t*)smem_raw;
  bf16_t* Xl   = lds + X_OFF;
  bf16_t* Ql   = lds + Q_OFF;
  bf16_t* Kl   = lds + K_OFF;
  bf16_t* Pl   = lds + P_OFF;     // overlay (valid after B2)
  bf16_t* VOtl = lds + VOT_OFF;   // overlay (valid after B2)

  const int tid  = threadIdx.x;
  const int wave = tid >> 6;           // 0..7
  const int lane = tid & 63;
  const int l15  = lane & 15;
  const int lg   = lane >> 4;          // 0..3

  const int blk = blockIdx.x;
  const int b   = blk >> 8;
  const int rem = blk & 255;
  const int wi  = rem >> 4, wj = rem & 15;

  // zero pad rows 49..63 of X
  for (int idx = tid; idx < 15 * 100; idx += 512) {
    int row = 49 + idx / 100, c2 = (idx % 100) * 2;
    *(unsigned int*)&Xl[row * XLD + c2] = 0u;
  }
  // stage window tokens (roll -3,-3 folded into the gather), f32 -> bf16
  for (int idx = tid; idx < 49 * 48; idx += 512) {
    int t = idx / 48, q4 = idx % 48;
    int hs = wi * 7 + t / 7 + SHIFT; if (hs >= HW) hs -= HW;
    int ws2 = wj * 7 + t % 7 + SHIFT; if (ws2 >= HW) ws2 -= HW;
    const float4 v = *(const float4*)&x[(((b * HW + hs) * HW) + ws2) * CH + q4 * 4];
    bf16x4 pk = { (bf16_t)v.x, (bf16_t)v.y, (bf16_t)v.z, (bf16_t)v.w };
    *(bf16x4*)&Xl[t * XLD + q4 * 4] = pk;
  }

  const int wc = wave & 3;             // phase-Y c-block (3 tiles each)
  const int wt = wave >> 2;            // phase-Y t-block (2 tiles each)
  f32x4 yacc[3][2] = {};               // persistent output accumulators

  for (int h = 0; h < NH; ++h) {
    __syncthreads();
    // ---- Phase A: Q^T-GEMM (waves 0-3) / K^T-GEMM (waves 4-7)
    // D[d,t] = sum_c W^T[d,c] X[t,c]; packed b64 write into [t][d] row-major.
    {
      const int isK = wave >> 2;
      const int w2  = wave & 3;
      const bf16_t* wt_p = wts + ((isK * NH + h) * CH * CH);
      const float* bias = (isK ? bk : bq) + h * CH;
      bf16_t* dst = isK ? Kl : Ql;
      f32x4 acc[3][4] = {};
#pragma unroll
      for (int ks = 0; ks < 6; ++ks) {
        bf16x8 af[3], bfr[4];
#pragma unroll
        for (int mi = 0; mi < 3; ++mi) {
          int d = (w2 * 3 + mi) * 16 + l15;
          af[mi] = *(const bf16x8*)&wt_p[d * CH + ks * 32 + lg * 8];
        }
#pragma unroll
        for (int ni = 0; ni < 4; ++ni)
          bfr[ni] = *(const bf16x8*)&Xl[(ni * 16 + l15) * XLD + ks * 32 + lg * 8];
#pragma unroll
        for (int mi = 0; mi < 3; ++mi)
#pragma unroll
          for (int ni = 0; ni < 4; ++ni)
            acc[mi][ni] = __builtin_amdgcn_mfma_f32_16x16x32_bf16(af[mi], bfr[ni], acc[mi][ni], 0, 0, 0);
      }
#pragma unroll
      for (int mi = 0; mi < 3; ++mi) {
        int d0 = (w2 * 3 + mi) * 16 + lg * 4;
        float b0 = bias[d0], b1 = bias[d0 + 1], b2 = bias[d0 + 2], b3 = bias[d0 + 3];
#pragma unroll
        for (int ni = 0; ni < 4; ++ni) {
          int t = ni * 16 + l15;
          bf16x4 pk = { (bf16_t)(acc[mi][ni][0] + b0), (bf16_t)(acc[mi][ni][1] + b1),
                        (bf16_t)(acc[mi][ni][2] + b2), (bf16_t)(acc[mi][ni][3] + b3) };
          *(bf16x4*)&dst[t * XLD + d0] = pk;
        }
      }
    }
    __syncthreads();
    // ---- Phase B (compute only, results stay in registers):
    //   waves 0-3: scores + in-register softmax; waves 4-7: VO-GEMM (X x U^h)
    f32x4 vacc[4][3] = {};
    bf16x4 psave[4];
    const bf16_t* U_h = wts + ((2 * NH + h) * CH * CH);
    if (wave < 4) {
      const int it = wave;
      f32x4 sacc[4] = {};
#pragma unroll
      for (int ks = 0; ks < 6; ++ks) {
        bf16x8 bq8 = *(const bf16x8*)&Ql[(it * 16 + l15) * XLD + ks * 32 + lg * 8];
#pragma unroll
        for (int mj = 0; mj < 4; ++mj) {
          bf16x8 ak = *(const bf16x8*)&Kl[(mj * 16 + l15) * XLD + ks * 32 + lg * 8];
          sacc[mj] = __builtin_amdgcn_mfma_f32_16x16x32_bf16(ak, bq8, sacc[mj], 0, 0, 0);
        }
      }
      const float scale = 0.07216878364870322f;  // 1/sqrt(192)
      float mx = -1e30f;
#pragma unroll
      for (int mj = 0; mj < 4; ++mj)
#pragma unroll
        for (int r = 0; r < 4; ++r) {
          int j = mj * 16 + lg * 4 + r;
          if (j < 49) mx = fmaxf(mx, sacc[mj][r]);
        }
      mx = fmaxf(mx, __shfl_xor(mx, 16));
      mx = fmaxf(mx, __shfl_xor(mx, 32));
      float p[4][4];
      float sum = 0.f;
#pragma unroll
      for (int mj = 0; mj < 4; ++mj)
#pragma unroll
        for (int r = 0; r < 4; ++r) {
          int j = mj * 16 + lg * 4 + r;
          float e = (j < 49) ? __expf((sacc[mj][r] - mx) * scale) : 0.f;
          p[mj][r] = e;
          sum += e;
        }
      sum += __shfl_xor(sum, 16);
      sum += __shfl_xor(sum, 32);
      float inv = 1.f / sum;
#pragma unroll
      for (int mj = 0; mj < 4; ++mj) {
        bf16x4 pk = { (bf16_t)(p[mj][0] * inv), (bf16_t)(p[mj][1] * inv),
                      (bf16_t)(p[mj][2] * inv), (bf16_t)(p[mj][3] * inv) };
        psave[mj] = pk;
      }
    } else {
      const int wv = wave - 4;
#pragma unroll
      for (int ks = 0; ks < 6; ++ks) {
        bf16x8 af[4], bfr[3];
#pragma unroll
        for (int mi = 0; mi < 4; ++mi)
          af[mi] = *(const bf16x8*)&Xl[(mi * 16 + l15) * XLD + ks * 32 + lg * 8];
#pragma unroll
        for (int ni = 0; ni < 3; ++ni) {
          int c = (wv * 3 + ni) * 16 + l15;
          bfr[ni] = *(const bf16x8*)&U_h[c * CH + ks * 32 + lg * 8];
        }
#pragma unroll
        for (int mi = 0; mi < 4; ++mi)
#pragma unroll
          for (int ni = 0; ni < 3; ++ni)
            vacc[mi][ni] = __builtin_amdgcn_mfma_f32_16x16x32_bf16(af[mi], bfr[ni], vacc[mi][ni], 0, 0, 0);
      }
    }
    __syncthreads();   // all Q/K/X reads of phase B are drained here
    // ---- Phase B2: write P and VOt into the dead Q/K region
    if (wave < 4) {
      int i = wave * 16 + l15;
#pragma unroll
      for (int mj = 0; mj < 4; ++mj)
        *(bf16x4*)&Pl[i * ULD + mj * 16 + lg * 4] = psave[mj];
    } else {
      const int wv = wave - 4;
      const float* bu_h = bu + h * CH;
#pragma unroll
      for (int ni = 0; ni < 3; ++ni) {
        int c = (wv * 3 + ni) * 16 + l15;
        float bb = bu_h[c];
#pragma unroll
        for (int mi = 0; mi < 4; ++mi) {
          int s0 = mi * 16 + lg * 4;
          bf16x4 pk = { (bf16_t)(vacc[mi][ni][0] + bb), (bf16_t)(vacc[mi][ni][1] + bb),
                        (bf16_t)(vacc[mi][ni][2] + bb), (bf16_t)(vacc[mi][ni][3] + bb) };
          *(bf16x4*)&VOtl[c * ULD + s0] = pk;
        }
      }
    }
    __syncthreads();
    // ---- Phase Y: yacc[c,t] += sum_s VOt[c,s] P[t,s]
    {
#pragma unroll
      for (int ks = 0; ks < 2; ++ks) {
        bf16x8 af[3], bfr[2];
#pragma unroll
        for (int mi = 0; mi < 3; ++mi)
          af[mi] = *(const bf16x8*)&VOtl[((wc * 3 + mi) * 16 + l15) * ULD + ks * 32 + lg * 8];
#pragma unroll
        for (int ni = 0; ni < 2; ++ni)
          bfr[ni] = *(const bf16x8*)&Pl[((wt * 2 + ni) * 16 + l15) * ULD + ks * 32 + lg * 8];
#pragma unroll
        for (int mi = 0; mi < 3; ++mi)
#pragma unroll
          for (int ni = 0; ni < 2; ++ni)
            yacc[mi][ni] = __builtin_amdgcn_mfma_f32_16x16x32_bf16(af[mi], bfr[ni], yacc[mi][ni], 0, 0, 0);
      }
    }
  }

  // ---- epilogue: +bo, plain-reshape merge + roll(+3,+3), packed f32x4 stores
#pragma unroll
  for (int ni = 0; ni < 2; ++ni) {
    int t = (wt * 2 + ni) * 16 + l15;
    if (t < 49) {
      int pos = rem * 49 + t;
      int hp = pos / 112, wp = pos % 112;
      hp += SHIFT; if (hp >= HW) hp -= HW;
      wp += SHIFT; if (wp >= HW) wp -= HW;
      float* op = out + (((b * HW + hp) * HW) + wp) * CH;
#pragma unroll
      for (int mi = 0; mi < 3; ++mi) {
        int c0 = (wc * 3 + mi) * 16 + lg * 4;
        f32x4 v = yacc[mi][ni];
        v[0] += bo[c0]; v[1] += bo[c0 + 1]; v[2] += bo[c0 + 2]; v[3] += bo[c0 + 3];
        *(f32x4*)&op[c0] = v;
      }
    }
  }
}

extern "C" void kernel_launch(void* const* d_in, const int* in_sizes, int n_in,
                              void* d_out, int out_size, void* d_ws, size_t ws_size,
                              hipStream_t stream) {
  const float* x  = (const float*)d_in[0];
  const float* Wq = (const float*)d_in[1];
  const float* bq = (const float*)d_in[2];
  const float* Wk = (const float*)d_in[3];
  const float* bk = (const float*)d_in[4];
  const float* Wv = (const float*)d_in[5];
  const float* bv = (const float*)d_in[6];
  const float* Wo = (const float*)d_in[7];
  const float* bo = (const float*)d_in[8];
  float* out = (float*)d_out;
  bf16_t* wts = (bf16_t*)d_ws;                       // 1.33 MB
  float*  bu  = (float*)((char*)d_ws + BU_OFF_BYTES); // 4.6 KB

  const int per = NH * CH * CH;
  prep_w<<<(2 * per + 255) / 256, 256, 0, stream>>>(Wq, Wk, wts);
  prep_u<<<NH * CH, CH, 0, stream>>>(Wv, Wo, wts + 2 * per);
  prep_bu<<<NH, CH, 0, stream>>>(bv, Wo, bu);

  (void)hipFuncSetAttribute((const void*)swin_fused,
                            hipFuncAttributeMaxDynamicSharedMemorySize, LDS_BYTES);
  swin_fused<<<dim3(4096), dim3(512), LDS_BYTES, stream>>>(x, bq, bk, bo, wts, bu, out);
}